// Round 1
// baseline (151.609 us; speedup 1.0000x reference)
//
#include <hip/hip_runtime.h>
#include <stdint.h>

typedef unsigned long long u64;

#define B_ 32
#define N_ 512
#define FIN_ 80
#define FH_ 50
#define NH_ 3
#define FO_ 80
#define CAT_ 150

__device__ inline void fma4(float4& a, float s, const float4& w) {
  a.x += s * w.x; a.y += s * w.y; a.z += s * w.z; a.w += s * w.w;
}

__device__ inline void gload_lds16(const float* g, float* l) {
  __builtin_amdgcn_global_load_lds(
      (const __attribute__((address_space(1))) unsigned int*)g,
      (__attribute__((address_space(3))) unsigned int*)l, 16, 0, 0);
}

// ---------------- Kernel 1: per-head Wh = h @ Ws[h] (padded to 64 cols), e1h, e2h ----
__global__ __launch_bounds__(256) void k_prep(const float* __restrict__ h,
                                              const float* __restrict__ Ws,
                                              const float* __restrict__ attn_a,
                                              float* __restrict__ WhP,
                                              float* __restrict__ e1h,
                                              float* __restrict__ e2h) {
  __shared__ __align__(16) float hs[64 * FIN_];
  __shared__ __align__(16) float ws[FIN_ * 64];
  __shared__ __align__(16) float a1s[64];
  __shared__ __align__(16) float a2s[64];
  int x = blockIdx.x;
  const int rt = x & 7; x >>= 3;
  const int bb = x & 31; x >>= 5;
  const int hh = x;  // 0..2
  const int n0 = rt * 64;
  const int t = threadIdx.x;

  {  // h tile rows contiguous: straight vector copy
    const float4* src = (const float4*)(h + ((size_t)bb * N_ + n0) * FIN_);
    float4* dst = (float4*)hs;
    for (int i = t; i < 64 * FIN_ / 4; i += 256) dst[i] = src[i];
  }
  {  // Ws[hh] padded 80x64, zero cols >= 50
    const float* src = Ws + (size_t)hh * FIN_ * FH_;
    for (int i = t; i < FIN_ * 64; i += 256) {
      int k = i >> 6, c = i & 63;
      ws[i] = (c < FH_) ? src[k * FH_ + c] : 0.0f;
    }
  }
  if (t < 64) {
    a1s[t] = (t < FH_) ? attn_a[hh * 2 * FH_ + t] : 0.0f;
    a2s[t] = (t < FH_) ? attn_a[hh * 2 * FH_ + FH_ + t] : 0.0f;
  }
  __syncthreads();

  const int r = t >> 2, cq = t & 3;
  float4 acc[4];
  for (int i = 0; i < 4; ++i) acc[i] = make_float4(0.f, 0.f, 0.f, 0.f);
  const float4* ws4 = (const float4*)ws;
  #pragma unroll 4
  for (int k = 0; k < FIN_; ++k) {
    float hv = hs[r * FIN_ + k];
    #pragma unroll
    for (int i = 0; i < 4; ++i) fma4(acc[i], hv, ws4[k * 16 + cq * 4 + i]);
  }
  {
    float4* dst = (float4*)(WhP + (((size_t)hh * B_ + bb) * N_ + n0 + r) * 64);
    #pragma unroll
    for (int i = 0; i < 4; ++i) dst[cq * 4 + i] = acc[i];
  }
  const float4* a14 = (const float4*)a1s;
  const float4* a24 = (const float4*)a2s;
  float p1 = 0.f, p2 = 0.f;
  #pragma unroll
  for (int i = 0; i < 4; ++i) {
    float4 a1 = a14[cq * 4 + i], a2 = a24[cq * 4 + i], v = acc[i];
    p1 += v.x * a1.x + v.y * a1.y + v.z * a1.z + v.w * a1.w;
    p2 += v.x * a2.x + v.y * a2.y + v.z * a2.z + v.w * a2.w;
  }
  p1 += __shfl_xor(p1, 1); p1 += __shfl_xor(p1, 2);
  p2 += __shfl_xor(p2, 1); p2 += __shfl_xor(p2, 2);
  if (cq == 0) {
    size_t o = ((size_t)hh * B_ + bb) * N_ + n0 + r;
    e1h[o] = p1; e2h[o] = p2;
  }
}

// ---------------- Kernel 2: adj -> bitmask (u64 words, bit j of word j/64) --------
__global__ __launch_bounds__(256) void k_mask(const int* __restrict__ adj,
                                              u64* __restrict__ maskw) {
  const int t = threadIdx.x;
  const int w = t >> 6, l = t & 63;
  const int row = blockIdx.x * 4 + w;  // b*512 + i
  const int* src = adj + (size_t)row * N_;
  u64* dst = maskw + (size_t)row * 8;
  #pragma unroll
  for (int it = 0; it < 8; ++it) {
    int v = src[it * 64 + l];
    u64 m = __ballot(v != 0);
    if (l == 0) dst[it] = m;
  }
}

// ---------------- Kernel 3/6: fused masked softmax + PV ---------------------------
// Wh row stride FP (contiguous rows). Block = G*16 threads, 64 output rows/block.
// Each thread: 4 rows x 4 cols accumulator. Unnormalized PV + denominator on the fly.
template <int FP, int G, int FLIM, int OSTR, bool DOELU>
__global__ __launch_bounds__(G * 16) void k_attn(const float* __restrict__ Wh,
                                                 const float* __restrict__ e1,
                                                 const float* __restrict__ e2,
                                                 const u64* __restrict__ maskw,
                                                 float* __restrict__ out) {
  constexpr int BS = G * 16;
  __shared__ __align__(16) float whs[64 * FP];
  __shared__ __align__(16) float ps[64 * 64];
  __shared__ __align__(16) float e2s[N_];
  __shared__ float e1s[64];
  __shared__ float msx[64];
  __shared__ float invl[64];
  __shared__ float red[256];

  const int t = threadIdx.x;
  int x = blockIdx.x;
  const int rt = x & 7; x >>= 3;
  const int bb = x & 31; x >>= 5;
  const int hh = x;
  const int n0 = rt * 64;
  const float* whp = Wh + ((size_t)hh * B_ + bb) * N_ * FP;
  const float* e1p = e1 + ((size_t)hh * B_ + bb) * N_ + n0;
  const float* e2p = e2 + ((size_t)hh * B_ + bb) * N_;
  const u64* mbase = maskw + ((size_t)bb * N_ + n0) * 8;

  for (int i = t; i < N_; i += BS) e2s[i] = e2p[i];
  if (t < 64) e1s[t] = e1p[t];
  __syncthreads();

  // pass 1: masked max of e2 per row (no exp needed: lrelu is monotone)
  if (t < 256) {
    const int r = t & 63, k = t >> 6;
    const u64* mr = mbase + r * 8 + k * 2;
    float mx0 = -3e38f, mx1 = -3e38f;
    for (int w2 = 0; w2 < 2; ++w2) {
      u64 word = mr[w2];
      int jb = k * 128 + w2 * 64;
      for (int jj = 0; jj < 64; jj += 2) {
        float v0 = ((word >> jj) & 1ull) ? e2s[jb + jj] : -3e38f;
        float v1 = ((word >> (jj + 1)) & 1ull) ? e2s[jb + jj + 1] : -3e38f;
        mx0 = fmaxf(mx0, v0); mx1 = fmaxf(mx1, v1);
      }
    }
    red[t] = fmaxf(mx0, mx1);
  }
  __syncthreads();
  if (t < 64) {
    float mx = fmaxf(fmaxf(red[t], red[t + 64]), fmaxf(red[t + 128], red[t + 192]));
    float s = e1s[t] + mx;
    msx[t] = fmaxf(s, 0.2f * s);  // lrelu(s), alpha<1
  }
  __syncthreads();

  float lsum = 0.0f;
  float4 acc0 = make_float4(0, 0, 0, 0), acc1 = acc0, acc2 = acc0, acc3 = acc0;
  const int g = t % G, slot = t / G;
  const int wv = t >> 6, l = t & 63;

  for (int tt = 0; tt < 8; ++tt) {
    {  // async stage Wh j-tile (contiguous 64*FP floats)
      const float* src = whp + (size_t)(tt * 64) * FP;
      #pragma unroll
      for (int i = 0; i < 4; ++i) {
        int chunk = wv * 4 + i;  // waves*4 == FP/4 exactly
        gload_lds16(src + (size_t)(chunk * 64 + l) * 4, whs + chunk * 256);
      }
    }
    if (t < 256) {  // p tile: one exp per (row, j), plus running denominator
      const int r = t & 63, k = t >> 6;
      u64 word = mbase[r * 8 + tt] >> (k * 16);
      float e1r = e1s[r];
      float mr = msx[r];
      #pragma unroll
      for (int jj = 0; jj < 16; ++jj) {
        int j = tt * 64 + k * 16 + jj;
        float s = e1r + e2s[j];
        s = fmaxf(s, 0.2f * s);
        float arg = ((word >> jj) & 1ull) ? (s - mr) : -1e30f;  // exp -> 0 when masked
        float p = __expf(arg);
        lsum += p;
        ps[(k * 16 + jj) * 64 + r] = p;
      }
    }
    __syncthreads();  // drains global_load_lds (vmcnt) + publishes ps
    {
      const float4* wh4 = (const float4*)whs;
      const float4* p4 = (const float4*)ps;
      #pragma unroll 4
      for (int j = 0; j < 64; ++j) {
        float4 wv4 = wh4[j * (FP / 4) + g];
        float4 pv = p4[j * 16 + slot];
        fma4(acc0, pv.x, wv4);
        fma4(acc1, pv.y, wv4);
        fma4(acc2, pv.z, wv4);
        fma4(acc3, pv.w, wv4);
      }
    }
    __syncthreads();  // protect whs/ps before next tile overwrites
  }

  if (t < 256) red[t] = lsum;
  __syncthreads();
  if (t < 64) {
    float lv = red[t] + red[t + 64] + red[t + 128] + red[t + 192];
    invl[t] = (lv > 0.f) ? 1.0f / lv : 0.0f;
  }
  __syncthreads();

  {
    float4 av[4] = {acc0, acc1, acc2, acc3};
    #pragma unroll
    for (int ri = 0; ri < 4; ++ri) {
      int r = slot * 4 + ri;
      float sc = invl[r];
      float4 v = av[ri];
      v.x *= sc; v.y *= sc; v.z *= sc; v.w *= sc;
      if (DOELU) {
        v.x = v.x > 0.f ? v.x : __expf(v.x) - 1.f;
        v.y = v.y > 0.f ? v.y : __expf(v.y) - 1.f;
        v.z = v.z > 0.f ? v.z : __expf(v.z) - 1.f;
        v.w = v.w > 0.f ? v.w : __expf(v.w) - 1.f;
      }
      float* op = out + ((size_t)bb * N_ + n0 + r) * OSTR + hh * FLIM + g * 4;
      if (OSTR % 4 == 0) {  // 16B-aligned rows (output layer)
        if (g * 4 + 4 <= FLIM) *(float4*)op = v;
      } else {  // cat layout: stride 150 -> 8B alignment only
        if (g * 4 + 4 <= FLIM) {
          ((float2*)op)[0] = make_float2(v.x, v.y);
          ((float2*)op)[1] = make_float2(v.z, v.w);
        } else if (g * 4 + 2 <= FLIM) {
          ((float2*)op)[0] = make_float2(v.x, v.y);
        }
      }
    }
  }
}

// ---------------- Kernel 4: Wh2 = cat @ W_out  (W_out staged in LDS) --------------
__global__ __launch_bounds__(256) void k_gemm2(const float* __restrict__ cat,
                                               const float* __restrict__ Wout,
                                               float* __restrict__ Wh2) {
  __shared__ __align__(16) float wl[CAT_ * FO_];
  const int t = threadIdx.x;
  {
    const float4* src = (const float4*)Wout;
    float4* dst = (float4*)wl;
    for (int i = t; i < CAT_ * FO_ / 4; i += 256) dst[i] = src[i];
  }
  __syncthreads();
  const int r = t >> 2, cq = t & 3;
  const size_t row = (size_t)blockIdx.x * 64 + r;
  const float* cp = cat + row * CAT_;
  float4 acc[5];
  for (int i = 0; i < 5; ++i) acc[i] = make_float4(0, 0, 0, 0);
  const float4* wl4 = (const float4*)wl;
  #pragma unroll 2
  for (int k = 0; k < CAT_; ++k) {
    float cv = cp[k];
    #pragma unroll
    for (int i = 0; i < 5; ++i) fma4(acc[i], cv, wl4[k * 20 + cq * 5 + i]);
  }
  float4* dst = (float4*)(Wh2 + row * FO_);
  #pragma unroll
  for (int i = 0; i < 5; ++i) dst[cq * 5 + i] = acc[i];
}

// ---------------- Kernel 5: e1o/e2o = Wh2 . a_out halves --------------------------
__global__ __launch_bounds__(256) void k_ev(const float* __restrict__ Wh2,
                                            const float* __restrict__ a_out,
                                            float* __restrict__ e1o,
                                            float* __restrict__ e2o) {
  const int t = threadIdx.x;
  const int r = t >> 2, kq = t & 3;
  const size_t row = (size_t)blockIdx.x * 64 + r;
  const float4* src = (const float4*)(Wh2 + row * FO_);
  const float4* a1 = (const float4*)a_out;
  const float4* a2 = (const float4*)(a_out + FO_);
  float p1 = 0.f, p2 = 0.f;
  #pragma unroll
  for (int i = 0; i < 5; ++i) {
    float4 v = src[kq * 5 + i];
    float4 x = a1[kq * 5 + i], y = a2[kq * 5 + i];
    p1 += v.x * x.x + v.y * x.y + v.z * x.z + v.w * x.w;
    p2 += v.x * y.x + v.y * y.y + v.z * y.z + v.w * y.w;
  }
  p1 += __shfl_xor(p1, 1); p1 += __shfl_xor(p1, 2);
  p2 += __shfl_xor(p2, 1); p2 += __shfl_xor(p2, 2);
  if (kq == 0) { e1o[row] = p1; e2o[row] = p2; }
}

extern "C" void kernel_launch(void* const* d_in, const int* in_sizes, int n_in,
                              void* d_out, int out_size, void* d_ws, size_t ws_size,
                              hipStream_t stream) {
  const float* h    = (const float*)d_in[0];
  const int*   adj  = (const int*)d_in[1];
  const float* Ws   = (const float*)d_in[2];
  const float* aa   = (const float*)d_in[3];
  const float* Wout = (const float*)d_in[4];
  const float* aout = (const float*)d_in[5];

  char* ws = (char*)d_ws;
  float* WhP = (float*)(ws + 0);         // 3*32*512*64 f32  = 12,582,912 B
  float* e1h = (float*)(ws + 12582912);  // 3*32*512 f32     =    196,608 B
  float* e2h = (float*)(ws + 12779520);  //                  =    196,608 B
  u64*   mk  = (u64*)  (ws + 12976128);  // 32*512*8 u64     =  1,048,576 B
  float* cat = (float*)(ws + 14024704);  // 32*512*150 f32   =  9,830,400 B
  float* Wh2 = (float*)(ws + 23855104);  // 32*512*80 f32    =  5,242,880 B
  float* e1o = (float*)(ws + 29097984);  // 32*512 f32       =     65,536 B
  float* e2o = (float*)(ws + 29163520);  //                  =     65,536 B

  hipLaunchKernelGGL(k_prep, dim3(768), dim3(256), 0, stream, h, Ws, aa, WhP, e1h, e2h);
  hipLaunchKernelGGL(k_mask, dim3(4096), dim3(256), 0, stream, adj, mk);
  hipLaunchKernelGGL((k_attn<64, 16, 50, 150, true>), dim3(768), dim3(256), 0, stream,
                     WhP, e1h, e2h, mk, cat);
  hipLaunchKernelGGL(k_gemm2, dim3(256), dim3(256), 0, stream, cat, Wout, Wh2);
  hipLaunchKernelGGL(k_ev, dim3(256), dim3(256), 0, stream, Wh2, aout, e1o, e2o);
  hipLaunchKernelGGL((k_attn<80, 20, 80, 80, false>), dim3(256), dim3(320), 0, stream,
                     Wh2, e1o, e2o, mk, (float*)d_out);
}

// Round 2
// 106.329 us; speedup vs baseline: 1.4259x; 1.4259x over previous
//
#include <hip/hip_runtime.h>
#include <stdint.h>

typedef unsigned long long u64;
typedef __attribute__((ext_vector_type(8))) short short8;   // 8 x bf16 (4 VGPR)
typedef __attribute__((ext_vector_type(4))) float f32x4;    // MFMA C/D frag

#define B_ 32
#define N_ 512
#define FIN_ 80
#define FH_ 50
#define NH_ 3
#define FO_ 80
#define CAT_ 150

__device__ inline unsigned short f2bf(float f) {  // RNE float -> bf16 bits
  unsigned u = __float_as_uint(f);
  u += 0x7fffu + ((u >> 16) & 1u);
  return (unsigned short)(u >> 16);
}

__device__ inline void fma4(float4& a, float s, const float4& w) {
  a.x += s * w.x; a.y += s * w.y; a.z += s * w.z; a.w += s * w.w;
}

// ---------- Kernel 1: Wh = h @ Ws[h]; emit e1h/e2h (f32) + WhT (bf16, [col][j]) ----
__global__ __launch_bounds__(256) void k_prep(const float* __restrict__ h,
                                              const float* __restrict__ Ws,
                                              const float* __restrict__ attn_a,
                                              unsigned short* __restrict__ whT,
                                              float* __restrict__ e1h,
                                              float* __restrict__ e2h) {
  __shared__ __align__(16) float hs[64 * FIN_];   // reused as 64x64 transpose buffer
  __shared__ __align__(16) float ws[FIN_ * 64];
  __shared__ __align__(16) float a1s[64];
  __shared__ __align__(16) float a2s[64];
  int x = blockIdx.x;
  const int rt = x & 7; x >>= 3;
  const int bb = x & 31; x >>= 5;
  const int hh = x;  // 0..2
  const int n0 = rt * 64;
  const int t = threadIdx.x;

  {  // h tile rows contiguous
    const float4* src = (const float4*)(h + ((size_t)bb * N_ + n0) * FIN_);
    float4* dst = (float4*)hs;
    for (int i = t; i < 64 * FIN_ / 4; i += 256) dst[i] = src[i];
  }
  {  // Ws[hh] padded 80x64, zero cols >= 50
    const float* src = Ws + (size_t)hh * FIN_ * FH_;
    for (int i = t; i < FIN_ * 64; i += 256) {
      int k = i >> 6, c = i & 63;
      ws[i] = (c < FH_) ? src[k * FH_ + c] : 0.0f;
    }
  }
  if (t < 64) {
    a1s[t] = (t < FH_) ? attn_a[hh * 2 * FH_ + t] : 0.0f;
    a2s[t] = (t < FH_) ? attn_a[hh * 2 * FH_ + FH_ + t] : 0.0f;
  }
  __syncthreads();

  const int r = t >> 2, cq = t & 3;   // r = local j row, cq = col quad
  float4 acc[4];
  for (int i = 0; i < 4; ++i) acc[i] = make_float4(0.f, 0.f, 0.f, 0.f);
  const float4* ws4 = (const float4*)ws;
  #pragma unroll 4
  for (int k = 0; k < FIN_; ++k) {
    float hv = hs[r * FIN_ + k];
    #pragma unroll
    for (int i = 0; i < 4; ++i) fma4(acc[i], hv, ws4[k * 16 + cq * 4 + i]);
  }
  // e1/e2 dot
  {
    const float4* a14 = (const float4*)a1s;
    const float4* a24 = (const float4*)a2s;
    float p1 = 0.f, p2 = 0.f;
    #pragma unroll
    for (int i = 0; i < 4; ++i) {
      float4 a1 = a14[cq * 4 + i], a2 = a24[cq * 4 + i], v = acc[i];
      p1 += v.x * a1.x + v.y * a1.y + v.z * a1.z + v.w * a1.w;
      p2 += v.x * a2.x + v.y * a2.y + v.z * a2.z + v.w * a2.w;
    }
    p1 += __shfl_xor(p1, 1); p1 += __shfl_xor(p1, 2);
    p2 += __shfl_xor(p2, 1); p2 += __shfl_xor(p2, 2);
    if (cq == 0) {
      size_t o = ((size_t)hh * B_ + bb) * N_ + n0 + r;
      e1h[o] = p1; e2h[o] = p2;
    }
  }
  __syncthreads();   // done reading hs/ws; reuse hs as transpose buffer
  float* tb = hs;    // tb[j][col], 64x64
  {
    float4* trow = (float4*)(tb + r * 64);
    #pragma unroll
    for (int i = 0; i < 4; ++i) trow[cq * 4 + i] = acc[i];
  }
  __syncthreads();
  // granule emit: WhT[(hh,bb) slice][col][512 j] bf16, this block owns j in [n0,n0+64)
  for (int g = t; g < 512; g += 256) {
    const int col = g >> 3, jg = g & 7;
    unsigned short pk[8];
    #pragma unroll
    for (int e = 0; e < 8; ++e) pk[e] = f2bf(tb[(jg * 8 + e) * 64 + col]);
    uint4 o;
    o.x = (unsigned)pk[0] | ((unsigned)pk[1] << 16);
    o.y = (unsigned)pk[2] | ((unsigned)pk[3] << 16);
    o.z = (unsigned)pk[4] | ((unsigned)pk[5] << 16);
    o.w = (unsigned)pk[6] | ((unsigned)pk[7] << 16);
    *(uint4*)&whT[(((size_t)hh * B_ + bb) * 64 + col) * 512 + n0 + jg * 8] = o;
  }
}

// ---------- Kernel 2: adj -> bitmask ----------------------------------------------
__global__ __launch_bounds__(256) void k_mask(const int* __restrict__ adj,
                                              u64* __restrict__ maskw) {
  const int t = threadIdx.x;
  const int w = t >> 6, l = t & 63;
  const int row = blockIdx.x * 4 + w;
  const int* src = adj + (size_t)row * N_;
  u64* dst = maskw + (size_t)row * 8;
  #pragma unroll
  for (int it = 0; it < 8; ++it) {
    int v = src[it * 64 + l];
    u64 m = __ballot(v != 0);
    if (l == 0) dst[it] = m;
  }
}

// ---------- Kernel 3/5: MFMA masked-softmax attention -----------------------------
// 4 waves/block, 16 rows/wave, 64 rows/block, full j range (512).
// A(P) built in registers; B(WhT bf16) loaded straight from global; no PV barriers.
template <int FP, int CT, int FLIM, int OSTR, bool DOELU, int GRPX>
__global__ __launch_bounds__(256) void k_attn(const unsigned short* __restrict__ whT,
                                              const float* __restrict__ e1,
                                              const float* __restrict__ e2,
                                              const u64* __restrict__ maskw,
                                              float* __restrict__ out) {
  __shared__ __align__(16) float e2s[N_];
  // XCD-bijective swizzle: keep the 8 row-tiles of one (hh,bb) slice on one XCD
  int x = (int)((blockIdx.x & 7) * GRPX + (blockIdx.x >> 3));
  const int rt = x & 7; x >>= 3;
  const int bb = x & 31; x >>= 5;
  const int hh = x;
  const int n0 = rt * 64;
  const int t = threadIdx.x;
  const int l = t & 63, wid = t >> 6;
  const int q = l >> 4, rl = l & 15;

  const float* e2p = e2 + ((size_t)hh * B_ + bb) * N_;
  for (int i = t; i < N_ / 4; i += 256) ((float4*)e2s)[i] = ((const float4*)e2p)[i];
  __syncthreads();

  const int row = n0 + wid * 16 + rl;                       // row index in [0,512)
  const float e1r = e1[((size_t)hh * B_ + bb) * N_ + row];
  const u64* mr = maskw + ((size_t)bb * N_ + row) * 8;

  // per-wave masked max of e2 for this row (lane covers j-quarter q)
  float mx = -3e38f;
  {
    u64 w0 = mr[2 * q], w1 = mr[2 * q + 1];
    #pragma unroll
    for (int w8 = 0; w8 < 16; ++w8) {
      u64 w = (w8 < 8) ? w0 : w1;
      unsigned byte = (unsigned)(w >> ((w8 & 7) * 8)) & 0xffu;
      const int jb = q * 128 + w8 * 8;
      float4 va = *(const float4*)&e2s[jb];
      float4 vb = *(const float4*)&e2s[jb + 4];
      mx = fmaxf(mx, (byte & 1u)   ? va.x : -3e38f);
      mx = fmaxf(mx, (byte & 2u)   ? va.y : -3e38f);
      mx = fmaxf(mx, (byte & 4u)   ? va.z : -3e38f);
      mx = fmaxf(mx, (byte & 8u)   ? va.w : -3e38f);
      mx = fmaxf(mx, (byte & 16u)  ? vb.x : -3e38f);
      mx = fmaxf(mx, (byte & 32u)  ? vb.y : -3e38f);
      mx = fmaxf(mx, (byte & 64u)  ? vb.z : -3e38f);
      mx = fmaxf(mx, (byte & 128u) ? vb.w : -3e38f);
    }
  }
  mx = fmaxf(mx, __shfl_xor(mx, 16));
  mx = fmaxf(mx, __shfl_xor(mx, 32));
  const float s0 = e1r + mx;
  const float msx = fmaxf(s0, 0.2f * s0);   // lrelu(max score), alpha = 0.2 < 1

  f32x4 acc[CT];
  #pragma unroll
  for (int c = 0; c < CT; ++c) acc[c] = (f32x4){0.f, 0.f, 0.f, 0.f};
  float lsum = 0.f;

  const unsigned short* wb = whT + ((size_t)hh * B_ + bb) * FP * 512;

  for (int tt = 0; tt < 8; ++tt) {  // j-tiles of 64
    // B fragments straight from global (16B contiguous per lane, L2-resident)
    short8 bf[CT][2];
    #pragma unroll
    for (int c = 0; c < CT; ++c) {
      const unsigned short* bp = wb + (size_t)(c * 16 + rl) * 512 + tt * 64 + q * 8;
      bf[c][0] = *(const short8*)bp;
      bf[c][1] = *(const short8*)(bp + 32);
    }
    // A fragments in registers: p = exp(lrelu(e1+e2) - msx), masked -> 0
    u64 word = mr[tt];
    short8 af[2];
    #pragma unroll
    for (int s = 0; s < 2; ++s) {
      unsigned byte = (unsigned)(word >> (s * 32 + q * 8)) & 0xffu;
      const int jb = tt * 64 + s * 32 + q * 8;
      float4 va = *(const float4*)&e2s[jb];
      float4 vb = *(const float4*)&e2s[jb + 4];
      float ev[8] = {va.x, va.y, va.z, va.w, vb.x, vb.y, vb.z, vb.w};
      #pragma unroll
      for (int e = 0; e < 8; ++e) {
        float sv = e1r + ev[e];
        sv = fmaxf(sv, 0.2f * sv);
        float arg = ((byte >> e) & 1u) ? (sv - msx) : -1e30f;
        float p = __expf(arg);
        lsum += p;
        af[s][e] = (short)f2bf(p);
      }
    }
    #pragma unroll
    for (int c = 0; c < CT; ++c) {
      acc[c] = __builtin_amdgcn_mfma_f32_16x16x32_bf16(af[0], bf[c][0], acc[c], 0, 0, 0);
      acc[c] = __builtin_amdgcn_mfma_f32_16x16x32_bf16(af[1], bf[c][1], acc[c], 0, 0, 0);
    }
  }

  // denominator: sum over the 4 quarter-lanes of this row
  float rs = lsum;
  rs += __shfl_xor(rs, 16);
  rs += __shfl_xor(rs, 32);
  const float inv = rs > 0.f ? 1.f / rs : 0.f;

  const size_t orow0 = (size_t)bb * N_ + n0 + wid * 16;
  #pragma unroll
  for (int r = 0; r < 4; ++r) {
    const float invr = __shfl(inv, q * 4 + r);  // lane q*4+r holds that row's sum
    const size_t ob = (orow0 + q * 4 + r) * OSTR + hh * FLIM;
    #pragma unroll
    for (int c = 0; c < CT; ++c) {
      const int col = c * 16 + rl;
      if (col < FLIM) {
        float v = acc[c][r] * invr;
        if (DOELU) v = v > 0.f ? v : __expf(v) - 1.f;
        out[ob + col] = v;
      }
    }
  }
}

// ---------- Kernel 4: Wh2 = cat @ W_out (+ e1o/e2o dots + bf16 transpose) ---------
__global__ __launch_bounds__(256) void k_gemm2(const float* __restrict__ cat,
                                               const float* __restrict__ Wout,
                                               const float* __restrict__ a_out,
                                               unsigned short* __restrict__ wh2T,
                                               float* __restrict__ e1o,
                                               float* __restrict__ e2o) {
  __shared__ __align__(16) float wl[CAT_ * FO_];
  __shared__ __align__(16) float tb[64 * FO_];
  const int t = threadIdx.x;
  {
    const float4* src = (const float4*)Wout;
    float4* dst = (float4*)wl;
    for (int i = t; i < CAT_ * FO_ / 4; i += 256) dst[i] = src[i];
  }
  __syncthreads();
  const int r = t >> 2, cq = t & 3;
  const size_t row = (size_t)blockIdx.x * 64 + r;
  const float* cp = cat + row * CAT_;
  float4 acc[5];
  for (int i = 0; i < 5; ++i) acc[i] = make_float4(0, 0, 0, 0);
  const float4* wl4 = (const float4*)wl;
  #pragma unroll 2
  for (int k = 0; k < CAT_; ++k) {
    float cv = cp[k];
    #pragma unroll
    for (int i = 0; i < 5; ++i) fma4(acc[i], cv, wl4[k * 20 + cq * 5 + i]);
  }
  // e1o/e2o (was k_ev)
  {
    const float4* a1 = (const float4*)a_out;
    const float4* a2 = (const float4*)(a_out + FO_);
    float p1 = 0.f, p2 = 0.f;
    #pragma unroll
    for (int i = 0; i < 5; ++i) {
      float4 v = acc[i];
      float4 xx = a1[cq * 5 + i], yy = a2[cq * 5 + i];
      p1 += v.x * xx.x + v.y * xx.y + v.z * xx.z + v.w * xx.w;
      p2 += v.x * yy.x + v.y * yy.y + v.z * yy.z + v.w * yy.w;
    }
    p1 += __shfl_xor(p1, 1); p1 += __shfl_xor(p1, 2);
    p2 += __shfl_xor(p2, 1); p2 += __shfl_xor(p2, 2);
    if (cq == 0) { e1o[row] = p1; e2o[row] = p2; }
  }
  // transpose to bf16 Wh2T[bb][col][512 j]
  {
    float4* trow = (float4*)(tb + r * FO_);
    #pragma unroll
    for (int i = 0; i < 5; ++i) trow[cq * 5 + i] = acc[i];
  }
  __syncthreads();
  const int bb2 = blockIdx.x >> 3, jt = blockIdx.x & 7;
  for (int g = t; g < 640; g += 256) {
    const int col = g >> 3, jg = g & 7;
    unsigned short pk[8];
    #pragma unroll
    for (int e = 0; e < 8; ++e) pk[e] = f2bf(tb[(jg * 8 + e) * FO_ + col]);
    uint4 o;
    o.x = (unsigned)pk[0] | ((unsigned)pk[1] << 16);
    o.y = (unsigned)pk[2] | ((unsigned)pk[3] << 16);
    o.z = (unsigned)pk[4] | ((unsigned)pk[5] << 16);
    o.w = (unsigned)pk[6] | ((unsigned)pk[7] << 16);
    *(uint4*)&wh2T[((size_t)bb2 * FO_ + col) * 512 + jt * 64 + jg * 8] = o;
  }
}

extern "C" void kernel_launch(void* const* d_in, const int* in_sizes, int n_in,
                              void* d_out, int out_size, void* d_ws, size_t ws_size,
                              hipStream_t stream) {
  const float* h    = (const float*)d_in[0];
  const int*   adj  = (const int*)d_in[1];
  const float* Ws   = (const float*)d_in[2];
  const float* aa   = (const float*)d_in[3];
  const float* Wout = (const float*)d_in[4];
  const float* aout = (const float*)d_in[5];

  char* ws = (char*)d_ws;
  unsigned short* whT  = (unsigned short*)(ws + 0);         // 3*32*64*512*2 = 6,291,456
  float* e1h           = (float*)(ws + 6291456);            //   196,608
  float* e2h           = (float*)(ws + 6488064);            //   196,608
  u64*   mk            = (u64*)  (ws + 6684672);            // 1,048,576
  float* cat           = (float*)(ws + 7733248);            // 9,830,400
  unsigned short* wh2T = (unsigned short*)(ws + 17563648);  // 2,621,440
  float* e1o           = (float*)(ws + 20185088);           //    65,536
  float* e2o           = (float*)(ws + 20250624);           //    65,536

  hipLaunchKernelGGL(k_prep, dim3(768), dim3(256), 0, stream, h, Ws, aa, whT, e1h, e2h);
  hipLaunchKernelGGL(k_mask, dim3(4096), dim3(256), 0, stream, adj, mk);
  hipLaunchKernelGGL((k_attn<64, 4, 50, 150, true, 96>), dim3(768), dim3(256), 0, stream,
                     whT, e1h, e2h, mk, cat);
  hipLaunchKernelGGL(k_gemm2, dim3(256), dim3(256), 0, stream, cat, Wout, aout, wh2T, e1o, e2o);
  hipLaunchKernelGGL((k_attn<80, 5, 80, 80, false, 32>), dim3(256), dim3(256), 0, stream,
                     wh2T, e1o, e2o, mk, (float*)d_out);
}